// Round 1
// baseline (348.397 us; speedup 1.0000x reference)
//
#include <hip/hip_runtime.h>
#include <hip/hip_bf16.h>
#include <math.h>

#define NN 4096
#define DIN 1024
#define NH 16
#define DH 64

typedef unsigned short u16;
typedef u16 u16x4 __attribute__((ext_vector_type(4)));
typedef u16 u16x8 __attribute__((ext_vector_type(8)));
typedef float fx4 __attribute__((ext_vector_type(4)));
typedef __bf16 bf16x8 __attribute__((ext_vector_type(8)));

__device__ __forceinline__ u16 f2b(float f) {
  unsigned u = __float_as_uint(f);
  u += 0x7fff + ((u >> 16) & 1);
  return (u16)(u >> 16);
}
__device__ __forceinline__ float b2f(u16 h) {
  return __uint_as_float(((unsigned)h) << 16);
}

// ---------------- cast f32 -> bf16 (flat) ----------------
__global__ __launch_bounds__(256) void cast_kernel(const float* __restrict__ in,
                                                   u16* __restrict__ out, int n4) {
  int i = blockIdx.x * 256 + threadIdx.x;
  if (i < n4) {
    fx4 v = reinterpret_cast<const fx4*>(in)[i];
    u16x4 o;
    o[0] = f2b(v[0]); o[1] = f2b(v[1]); o[2] = f2b(v[2]); o[3] = f2b(v[3]);
    reinterpret_cast<u16x4*>(out)[i] = o;
  }
}

// ---------------- transpose+cast f32[R][C] -> bf16[C][R] ----------------
__global__ __launch_bounds__(256) void tcast_kernel(const float* __restrict__ in,
                                                    u16* __restrict__ out, int R, int C) {
  __shared__ u16 tile[32][33];
  int bc = blockIdx.x * 32, br = blockIdx.y * 32;
  int tx = threadIdx.x & 31, ty = threadIdx.x >> 5;
  #pragma unroll
  for (int r = ty; r < 32; r += 8)
    tile[r][tx] = f2b(in[(size_t)(br + r) * C + bc + tx]);
  __syncthreads();
  #pragma unroll
  for (int r = ty; r < 32; r += 8)
    out[(size_t)(bc + r) * R + br + tx] = tile[tx][r];
}

// ---------------- transpose bf16[R][C] -> bf16[C][R] ----------------
__global__ __launch_bounds__(256) void tb16_kernel(const u16* __restrict__ in,
                                                   u16* __restrict__ out, int R, int C) {
  __shared__ u16 tile[32][33];
  int bc = blockIdx.x * 32, br = blockIdx.y * 32;
  int tx = threadIdx.x & 31, ty = threadIdx.x >> 5;
  #pragma unroll
  for (int r = ty; r < 32; r += 8)
    tile[r][tx] = in[(size_t)(br + r) * C + bc + tx];
  __syncthreads();
  #pragma unroll
  for (int r = ty; r < 32; r += 8)
    out[(size_t)(bc + r) * R + br + tx] = tile[tx][r];
}

// ---------------- bf16 GEMM: C[M][N] = A[M][K] * BT[N][K]^T ----------------
// EPI=0: write bf16 C.  EPI=1: f32 out = elu(C + bias[col]).
template <int EPI>
__global__ __launch_bounds__(256) void gemm_bt(const u16* __restrict__ A,
                                               const u16* __restrict__ BT,
                                               void* __restrict__ Cv,
                                               const float* __restrict__ bias,
                                               int M, int N, int K) {
  __shared__ __align__(16) u16 As[128][40];
  __shared__ __align__(16) u16 Bs[128][40];
  const int tid = threadIdx.x;
  const int i0 = blockIdx.x * 128, n0 = blockIdx.y * 128;
  const int w = tid >> 6, l = tid & 63;
  const int wr = w >> 1, wc = w & 1;
  const int lr = l & 15, lk = (l >> 4) * 8;
  const int srow = tid >> 1, sk = (tid & 1) * 16;
  fx4 acc[4][4] = {};
  const u16* ga = A + (size_t)(i0 + srow) * K + sk;
  const u16* gb = BT + (size_t)(n0 + srow) * K + sk;
  for (int k0 = 0; k0 < K; k0 += 32) {
    u16x8 a0 = *reinterpret_cast<const u16x8*>(ga + k0);
    u16x8 a1 = *reinterpret_cast<const u16x8*>(ga + k0 + 8);
    u16x8 b0 = *reinterpret_cast<const u16x8*>(gb + k0);
    u16x8 b1 = *reinterpret_cast<const u16x8*>(gb + k0 + 8);
    __syncthreads();
    *reinterpret_cast<u16x8*>(&As[srow][sk]) = a0;
    *reinterpret_cast<u16x8*>(&As[srow][sk + 8]) = a1;
    *reinterpret_cast<u16x8*>(&Bs[srow][sk]) = b0;
    *reinterpret_cast<u16x8*>(&Bs[srow][sk + 8]) = b1;
    __syncthreads();
    bf16x8 af[4], bfr[4];
    #pragma unroll
    for (int mi = 0; mi < 4; mi++)
      af[mi] = *reinterpret_cast<const bf16x8*>(&As[wr * 64 + mi * 16 + lr][lk]);
    #pragma unroll
    for (int ni = 0; ni < 4; ni++)
      bfr[ni] = *reinterpret_cast<const bf16x8*>(&Bs[wc * 64 + ni * 16 + lr][lk]);
    #pragma unroll
    for (int mi = 0; mi < 4; mi++)
      #pragma unroll
      for (int ni = 0; ni < 4; ni++)
        acc[mi][ni] = __builtin_amdgcn_mfma_f32_16x16x32_bf16(af[mi], bfr[ni], acc[mi][ni], 0, 0, 0);
  }
  const int orow = wr * 64 + (l >> 4) * 4;
  const int ocol = wc * 64 + lr;
  if (EPI == 0) {
    u16* Cb = (u16*)Cv;
    #pragma unroll
    for (int mi = 0; mi < 4; mi++)
      #pragma unroll
      for (int r = 0; r < 4; r++)
        #pragma unroll
        for (int ni = 0; ni < 4; ni++)
          Cb[(size_t)(i0 + orow + mi * 16 + r) * N + n0 + ocol + ni * 16] = f2b(acc[mi][ni][r]);
  } else {
    float* Cf = (float*)Cv;
    #pragma unroll
    for (int mi = 0; mi < 4; mi++)
      #pragma unroll
      for (int r = 0; r < 4; r++)
        #pragma unroll
        for (int ni = 0; ni < 4; ni++) {
          int col = n0 + ocol + ni * 16;
          float v = acc[mi][ni][r] + bias[col];
          Cf[(size_t)(i0 + orow + mi * 16 + r) * N + col] = v > 0.f ? v : expm1f(v);
        }
  }
}

// ---------------- per-head scalar scores ----------------
__global__ __launch_bounds__(256) void scores_kernel(const u16* __restrict__ seqb,
                                                     const float* __restrict__ a1,
                                                     const float* __restrict__ a2,
                                                     float* __restrict__ s1T,
                                                     float* __restrict__ s2T,
                                                     float* __restrict__ s2H) {
  int n = blockIdx.x, t = threadIdx.x;
  u16x4 v = reinterpret_cast<const u16x4*>(seqb)[n * 256 + t];
  fx4 w1 = reinterpret_cast<const fx4*>(a1)[t & 15];
  fx4 w2 = reinterpret_cast<const fx4*>(a2)[t & 15];
  float s1 = 0.f, s2 = 0.f;
  #pragma unroll
  for (int e = 0; e < 4; e++) {
    float f = b2f(v[e]);
    s1 += f * w1[e];
    s2 += f * w2[e];
  }
  #pragma unroll
  for (int off = 1; off < 16; off <<= 1) {
    s1 += __shfl_xor(s1, off);
    s2 += __shfl_xor(s2, off);
  }
  if ((t & 15) == 0) {
    int h = t >> 4;
    s1T[n * NH + h] = s1;
    s2T[n * NH + h] = s2;
    s2H[h * NN + n] = s2;
  }
}

// ---------------- softmax stats: m[h,i], 1/l[h,i] ----------------
__global__ __launch_bounds__(256) void stats_kernel(const float* __restrict__ adj,
                                                    const float* __restrict__ s1T,
                                                    const float* __restrict__ s2T,
                                                    float* __restrict__ mT,
                                                    float* __restrict__ invlT) {
  __shared__ float red[4][16];
  __shared__ float msh[16], csh[16];
  const int i = blockIdx.x, t = threadIdx.x, w = t >> 6, l = t & 63;
  const fx4* arow = reinterpret_cast<const fx4*>(adj + (size_t)i * NN);
  fx4 av[4];
  #pragma unroll
  for (int q = 0; q < 4; q++) av[q] = arow[t + 256 * q];
  float maxd[16];
  #pragma unroll
  for (int h = 0; h < 16; h++) maxd[h] = -3e38f;
  #pragma unroll
  for (int q = 0; q < 4; q++)
    #pragma unroll
    for (int e = 0; e < 4; e++)
      if (av[q][e] > 0.5f) {
        int j = (t + 256 * q) * 4 + e;
        const fx4* dr = reinterpret_cast<const fx4*>(s2T + j * NH);
        #pragma unroll
        for (int p = 0; p < 4; p++) {
          fx4 dv = dr[p];
          #pragma unroll
          for (int z = 0; z < 4; z++) maxd[p * 4 + z] = fmaxf(maxd[p * 4 + z], dv[z]);
        }
      }
  #pragma unroll
  for (int h = 0; h < 16; h++) {
    float v = maxd[h];
    #pragma unroll
    for (int off = 1; off < 64; off <<= 1) v = fmaxf(v, __shfl_xor(v, off));
    maxd[h] = v;
  }
  if (l == 0) {
    #pragma unroll
    for (int h = 0; h < 16; h++) red[w][h] = maxd[h];
  }
  __syncthreads();
  if (t < 16) {
    float mx = fmaxf(fmaxf(red[0][t], red[1][t]), fmaxf(red[2][t], red[3][t]));
    float c = s1T[i * NH + t];
    float m = c + mx;
    m = m > 0.f ? m : 0.2f * m;
    msh[t] = m;
    csh[t] = c;
  }
  __syncthreads();
  float cl[16], ml[16], lsum[16];
  #pragma unroll
  for (int h = 0; h < 16; h++) { cl[h] = csh[h]; ml[h] = msh[h]; lsum[h] = 0.f; }
  #pragma unroll
  for (int q = 0; q < 4; q++)
    #pragma unroll
    for (int e = 0; e < 4; e++)
      if (av[q][e] > 0.5f) {
        int j = (t + 256 * q) * 4 + e;
        const fx4* dr = reinterpret_cast<const fx4*>(s2T + j * NH);
        #pragma unroll
        for (int p = 0; p < 4; p++) {
          fx4 dv = dr[p];
          #pragma unroll
          for (int z = 0; z < 4; z++) {
            int h = p * 4 + z;
            float s = cl[h] + dv[z];
            s = s > 0.f ? s : 0.2f * s;
            lsum[h] += __expf(s - ml[h]);
          }
        }
      }
  #pragma unroll
  for (int h = 0; h < 16; h++) {
    float v = lsum[h];
    #pragma unroll
    for (int off = 1; off < 64; off <<= 1) v += __shfl_xor(v, off);
    lsum[h] = v;
  }
  if (l == 0) {
    #pragma unroll
    for (int h = 0; h < 16; h++) red[w][h] = lsum[h];
  }
  __syncthreads();
  if (t < 16) {
    float ltot = red[0][t] + red[1][t] + red[2][t] + red[3][t];
    mT[i * NH + t] = msh[t];
    invlT[i * NH + t] = 1.0f / ltot;
  }
}

// ---------------- fused P-build + PV matmul (per head, 64-row tile) ----------------
__global__ __launch_bounds__(256) void pv_kernel(const float* __restrict__ adj,
                                                 const u16* __restrict__ seqT,
                                                 const float* __restrict__ s1T,
                                                 const float* __restrict__ s2H,
                                                 const float* __restrict__ mT,
                                                 const float* __restrict__ invlT,
                                                 u16* __restrict__ hiddenb) {
  __shared__ __align__(16) u16 Ps[64][72];
  __shared__ __align__(16) u16 Ss[64][72];
  const int h = blockIdx.x & 15, it = blockIdx.x >> 4;
  const int i0 = it * 64;
  const int t = threadIdx.x, w = t >> 6, l = t & 63;
  const int lr = l & 15, lk = (l >> 4) * 8;
  const int pi = t >> 2, pjc = (t & 3) * 16;
  const float ci = s1T[(i0 + pi) * NH + h];
  const float mi = mT[(i0 + pi) * NH + h];
  const int sr = t >> 2, sc = (t & 3) * 16;
  const u16* gs = seqT + (size_t)(h * DH + sr) * NN + sc;
  const float* garow = adj + (size_t)(i0 + pi) * NN + pjc;
  const float* gdrow = s2H + (size_t)h * NN + pjc;
  fx4 acc[4] = {};
  for (int j0 = 0; j0 < NN; j0 += 64) {
    u16x8 sv0 = *reinterpret_cast<const u16x8*>(gs + j0);
    u16x8 sv1 = *reinterpret_cast<const u16x8*>(gs + j0 + 8);
    fx4 av[4], dv[4];
    #pragma unroll
    for (int q = 0; q < 4; q++) {
      av[q] = *reinterpret_cast<const fx4*>(garow + j0 + q * 4);
      dv[q] = *reinterpret_cast<const fx4*>(gdrow + j0 + q * 4);
    }
    __syncthreads();  // previous iteration's MFMA reads complete
    *reinterpret_cast<u16x8*>(&Ss[sr][sc]) = sv0;
    *reinterpret_cast<u16x8*>(&Ss[sr][sc + 8]) = sv1;
    u16x8 p0, p1;
    #pragma unroll
    for (int q = 0; q < 4; q++)
      #pragma unroll
      for (int z = 0; z < 4; z++) {
        float s = ci + dv[q][z];
        s = s > 0.f ? s : 0.2f * s;
        float p = (av[q][z] > 0.5f) ? __expf(s - mi) : 0.f;
        int idx = q * 4 + z;
        if (idx < 8) p0[idx] = f2b(p); else p1[idx - 8] = f2b(p);
      }
    *reinterpret_cast<u16x8*>(&Ps[pi][pjc]) = p0;
    *reinterpret_cast<u16x8*>(&Ps[pi][pjc + 8]) = p1;
    __syncthreads();  // Ps/Ss visible
    #pragma unroll
    for (int ks = 0; ks < 2; ks++) {
      bf16x8 af = *reinterpret_cast<const bf16x8*>(&Ps[w * 16 + lr][ks * 32 + lk]);
      #pragma unroll
      for (int ni = 0; ni < 4; ni++) {
        bf16x8 bfr = *reinterpret_cast<const bf16x8*>(&Ss[ni * 16 + lr][ks * 32 + lk]);
        acc[ni] = __builtin_amdgcn_mfma_f32_16x16x32_bf16(af, bfr, acc[ni], 0, 0, 0);
      }
    }
  }
  #pragma unroll
  for (int r = 0; r < 4; r++) {
    int il = w * 16 + (l >> 4) * 4 + r;
    float inv = invlT[(i0 + il) * NH + h];
    #pragma unroll
    for (int ni = 0; ni < 4; ni++)
      hiddenb[(size_t)(i0 + il) * DIN + h * DH + ni * 16 + lr] = f2b(acc[ni][r] * inv);
  }
}

extern "C" void kernel_launch(void* const* d_in, const int* in_sizes, int n_in,
                              void* d_out, int out_size, void* d_ws, size_t ws_size,
                              hipStream_t stream) {
  const float* x = (const float*)d_in[0];
  const float* adj = (const float*)d_in[1];
  const float* W_seq = (const float*)d_in[2];
  const float* a1 = (const float*)d_in[3];
  const float* a2 = (const float*)d_in[4];
  const float* W_out = (const float*)d_in[5];
  const float* b_out = (const float*)d_in[6];

  char* ws = (char*)d_ws;
  u16* xb   = (u16*)(ws);                       // 8 MB
  u16* wsT  = (u16*)(ws + (8u << 20));          // 2 MB
  u16* woT  = (u16*)(ws + (10u << 20));         // 2 MB
  u16* seqb = (u16*)(ws + (12u << 20));         // 8 MB
  u16* seqT = (u16*)(ws + (20u << 20));         // 8 MB
  u16* hid  = (u16*)(ws + (28u << 20));         // 8 MB
  float* s1T   = (float*)(ws + (36u << 20));
  float* s2T   = s1T + NN * NH;
  float* s2H   = s2T + NN * NH;
  float* mT    = s2H + NN * NH;
  float* invlT = mT + NN * NH;

  // 1. casts / transposes of weights and x
  cast_kernel<<<4096, 256, 0, stream>>>(x, xb, NN * DIN / 4);
  tcast_kernel<<<dim3(32, 32), 256, 0, stream>>>(W_seq, wsT, DIN, DIN);
  tcast_kernel<<<dim3(32, 32), 256, 0, stream>>>(W_out, woT, DIN, DIN);
  // 2. seq = x @ W_seq  (bf16 out)
  gemm_bt<0><<<dim3(32, 8), 256, 0, stream>>>(xb, wsT, (void*)seqb, nullptr, NN, DIN, DIN);
  // 3. per-head scores
  scores_kernel<<<4096, 256, 0, stream>>>(seqb, a1, a2, s1T, s2T, s2H);
  // 4. seq transpose for PV B-operand
  tb16_kernel<<<dim3(32, 128), 256, 0, stream>>>(seqb, seqT, NN, DIN);
  // 5. softmax stats
  stats_kernel<<<4096, 256, 0, stream>>>(adj, s1T, s2T, mT, invlT);
  // 6. fused P + PV
  pv_kernel<<<1024, 256, 0, stream>>>(adj, seqT, s1T, s2H, mT, invlT, hid);
  // 7. out = elu(hidden @ W_out + b_out)
  gemm_bt<1><<<dim3(32, 8), 256, 0, stream>>>(hid, woT, d_out, b_out, NN, DIN, DIN);
}

// Round 2
// 288.597 us; speedup vs baseline: 1.2072x; 1.2072x over previous
//
#include <hip/hip_runtime.h>
#include <hip/hip_bf16.h>
#include <math.h>

#define NN 4096
#define DIN 1024
#define NH 16
#define DH 64

typedef unsigned short u16;
typedef u16 u16x4 __attribute__((ext_vector_type(4)));
typedef u16 u16x8 __attribute__((ext_vector_type(8)));
typedef float fx4 __attribute__((ext_vector_type(4)));
typedef __bf16 bf16x8 __attribute__((ext_vector_type(8)));

__device__ __forceinline__ u16 f2b(float f) {
  unsigned u = __float_as_uint(f);
  u += 0x7fff + ((u >> 16) & 1);
  return (u16)(u >> 16);
}
__device__ __forceinline__ float b2f(u16 h) {
  return __uint_as_float(((unsigned)h) << 16);
}

// ---------------- cast f32 -> bf16 (flat) ----------------
__global__ __launch_bounds__(256) void cast_kernel(const float* __restrict__ in,
                                                   u16* __restrict__ out, int n4) {
  int i = blockIdx.x * 256 + threadIdx.x;
  if (i < n4) {
    fx4 v = reinterpret_cast<const fx4*>(in)[i];
    u16x4 o;
    o[0] = f2b(v[0]); o[1] = f2b(v[1]); o[2] = f2b(v[2]); o[3] = f2b(v[3]);
    reinterpret_cast<u16x4*>(out)[i] = o;
  }
}

// ---------------- transpose+cast f32[R][C] -> bf16[C][R] ----------------
__global__ __launch_bounds__(256) void tcast_kernel(const float* __restrict__ in,
                                                    u16* __restrict__ out, int R, int C) {
  __shared__ u16 tile[32][33];
  int bc = blockIdx.x * 32, br = blockIdx.y * 32;
  int tx = threadIdx.x & 31, ty = threadIdx.x >> 5;
  #pragma unroll
  for (int r = ty; r < 32; r += 8)
    tile[r][tx] = f2b(in[(size_t)(br + r) * C + bc + tx]);
  __syncthreads();
  #pragma unroll
  for (int r = ty; r < 32; r += 8)
    out[(size_t)(bc + r) * R + br + tx] = tile[tx][r];
}

// ---------------- transpose bf16[R][C] -> bf16[C][R] ----------------
__global__ __launch_bounds__(256) void tb16_kernel(const u16* __restrict__ in,
                                                   u16* __restrict__ out, int R, int C) {
  __shared__ u16 tile[32][33];
  int bc = blockIdx.x * 32, br = blockIdx.y * 32;
  int tx = threadIdx.x & 31, ty = threadIdx.x >> 5;
  #pragma unroll
  for (int r = ty; r < 32; r += 8)
    tile[r][tx] = in[(size_t)(br + r) * C + bc + tx];
  __syncthreads();
  #pragma unroll
  for (int r = ty; r < 32; r += 8)
    out[(size_t)(bc + r) * R + br + tx] = tile[tx][r];
}

// ---------------- bf16 GEMM: C[M][N] = A[M][K] * BT[N][K]^T ----------------
// EPI=0: write bf16 C.  EPI=1: f32 out = elu(C + bias[col]).
template <int EPI>
__global__ __launch_bounds__(256) void gemm_bt(const u16* __restrict__ A,
                                               const u16* __restrict__ BT,
                                               void* __restrict__ Cv,
                                               const float* __restrict__ bias,
                                               int M, int N, int K) {
  __shared__ __align__(16) u16 As[128][40];
  __shared__ __align__(16) u16 Bs[128][40];
  const int tid = threadIdx.x;
  const int i0 = blockIdx.x * 128, n0 = blockIdx.y * 128;
  const int w = tid >> 6, l = tid & 63;
  const int wr = w >> 1, wc = w & 1;
  const int lr = l & 15, lk = (l >> 4) * 8;
  const int srow = tid >> 1, sk = (tid & 1) * 16;
  fx4 acc[4][4] = {};
  const u16* ga = A + (size_t)(i0 + srow) * K + sk;
  const u16* gb = BT + (size_t)(n0 + srow) * K + sk;
  for (int k0 = 0; k0 < K; k0 += 32) {
    u16x8 a0 = *reinterpret_cast<const u16x8*>(ga + k0);
    u16x8 a1 = *reinterpret_cast<const u16x8*>(ga + k0 + 8);
    u16x8 b0 = *reinterpret_cast<const u16x8*>(gb + k0);
    u16x8 b1 = *reinterpret_cast<const u16x8*>(gb + k0 + 8);
    __syncthreads();
    *reinterpret_cast<u16x8*>(&As[srow][sk]) = a0;
    *reinterpret_cast<u16x8*>(&As[srow][sk + 8]) = a1;
    *reinterpret_cast<u16x8*>(&Bs[srow][sk]) = b0;
    *reinterpret_cast<u16x8*>(&Bs[srow][sk + 8]) = b1;
    __syncthreads();
    bf16x8 af[4], bfr[4];
    #pragma unroll
    for (int mi = 0; mi < 4; mi++)
      af[mi] = *reinterpret_cast<const bf16x8*>(&As[wr * 64 + mi * 16 + lr][lk]);
    #pragma unroll
    for (int ni = 0; ni < 4; ni++)
      bfr[ni] = *reinterpret_cast<const bf16x8*>(&Bs[wc * 64 + ni * 16 + lr][lk]);
    #pragma unroll
    for (int mi = 0; mi < 4; mi++)
      #pragma unroll
      for (int ni = 0; ni < 4; ni++)
        acc[mi][ni] = __builtin_amdgcn_mfma_f32_16x16x32_bf16(af[mi], bfr[ni], acc[mi][ni], 0, 0, 0);
  }
  const int orow = wr * 64 + (l >> 4) * 4;
  const int ocol = wc * 64 + lr;
  if (EPI == 0) {
    u16* Cb = (u16*)Cv;
    #pragma unroll
    for (int mi = 0; mi < 4; mi++)
      #pragma unroll
      for (int r = 0; r < 4; r++)
        #pragma unroll
        for (int ni = 0; ni < 4; ni++)
          Cb[(size_t)(i0 + orow + mi * 16 + r) * N + n0 + ocol + ni * 16] = f2b(acc[mi][ni][r]);
  } else {
    float* Cf = (float*)Cv;
    #pragma unroll
    for (int mi = 0; mi < 4; mi++)
      #pragma unroll
      for (int r = 0; r < 4; r++)
        #pragma unroll
        for (int ni = 0; ni < 4; ni++) {
          int col = n0 + ocol + ni * 16;
          float v = acc[mi][ni][r] + bias[col];
          Cf[(size_t)(i0 + orow + mi * 16 + r) * N + col] = v > 0.f ? v : expm1f(v);
        }
  }
}

// ---------------- per-head scalar scores ----------------
__global__ __launch_bounds__(256) void scores_kernel(const u16* __restrict__ seqb,
                                                     const float* __restrict__ a1,
                                                     const float* __restrict__ a2,
                                                     float* __restrict__ s1T,
                                                     float* __restrict__ s2H) {
  int n = blockIdx.x, t = threadIdx.x;
  u16x4 v = reinterpret_cast<const u16x4*>(seqb)[n * 256 + t];
  fx4 w1 = reinterpret_cast<const fx4*>(a1)[t & 15];
  fx4 w2 = reinterpret_cast<const fx4*>(a2)[t & 15];
  float s1 = 0.f, s2 = 0.f;
  #pragma unroll
  for (int e = 0; e < 4; e++) {
    float f = b2f(v[e]);
    s1 += f * w1[e];
    s2 += f * w2[e];
  }
  #pragma unroll
  for (int off = 1; off < 16; off <<= 1) {
    s1 += __shfl_xor(s1, off);
    s2 += __shfl_xor(s2, off);
  }
  if ((t & 15) == 0) {
    int h = t >> 4;
    s1T[n * NH + h] = s1;
    s2H[h * NN + n] = s2;
  }
}

// ---------------- per-head global max of d + exp tables ----------------
__global__ __launch_bounds__(256) void prep_kernel(const float* __restrict__ s2H,
                                                   float* __restrict__ Dmax,
                                                   float* __restrict__ Ep,
                                                   float* __restrict__ En) {
  __shared__ float red[4];
  const int h = blockIdx.x, t = threadIdx.x;
  const fx4* d = reinterpret_cast<const fx4*>(s2H + (size_t)h * NN);
  fx4 v[4];
  float mx = -3e38f;
  #pragma unroll
  for (int q = 0; q < 4; q++) {
    v[q] = d[t + 256 * q];
    #pragma unroll
    for (int z = 0; z < 4; z++) mx = fmaxf(mx, v[q][z]);
  }
  #pragma unroll
  for (int off = 1; off < 64; off <<= 1) mx = fmaxf(mx, __shfl_xor(mx, off));
  if ((t & 63) == 0) red[t >> 6] = mx;
  __syncthreads();
  mx = fmaxf(fmaxf(red[0], red[1]), fmaxf(red[2], red[3]));
  if (t == 0) Dmax[h] = mx;
  #pragma unroll
  for (int q = 0; q < 4; q++) {
    fx4 ep, en;
    #pragma unroll
    for (int z = 0; z < 4; z++) {
      ep[z] = __expf(v[q][z]);
      en[z] = __expf(0.2f * v[q][z]);
    }
    reinterpret_cast<fx4*>(Ep + (size_t)h * NN)[t + 256 * q] = ep;
    reinterpret_cast<fx4*>(En + (size_t)h * NN)[t + 256 * q] = en;
  }
}

// ---------------- fused P-build + PV matmul + softmax-denominator ----------------
__global__ __launch_bounds__(256) void pv_kernel(const float* __restrict__ adj,
                                                 const u16* __restrict__ seqT,
                                                 const float* __restrict__ s1T,
                                                 const float* __restrict__ Dmax,
                                                 const float* __restrict__ Ep,
                                                 const float* __restrict__ En,
                                                 u16* __restrict__ hiddenb) {
  __shared__ __align__(16) u16 Ps[64][72];
  __shared__ __align__(16) u16 Ss[64][72];
  __shared__ float linv[64];
  const int h = blockIdx.x & 15, it = blockIdx.x >> 4;
  const int i0 = it * 64;
  const int t = threadIdx.x, w = t >> 6, l = t & 63;
  const int lr = l & 15, lk = (l >> 4) * 8;
  const int pi = t >> 2, pjc = (t & 3) * 16;
  const float ci = s1T[(i0 + pi) * NH + h];
  const float Dm = Dmax[h];
  float mi = ci + Dm;
  mi = mi > 0.f ? mi : 0.2f * mi;
  const float Ai = __expf(ci - mi);
  const float Bi = __expf(0.2f * ci - mi);
  const float Ti = __expf(-mi);
  const int sr = t >> 2, sc = (t & 3) * 16;
  const u16* gs = seqT + (size_t)(h * DH + sr) * NN + sc;
  const float* garow = adj + (size_t)(i0 + pi) * NN + pjc;
  const float* gep = Ep + (size_t)h * NN + pjc;
  const float* gen = En + (size_t)h * NN + pjc;
  fx4 acc[4] = {};
  float lsum = 0.f;
  for (int j0 = 0; j0 < NN; j0 += 64) {
    u16x8 sv0 = *reinterpret_cast<const u16x8*>(gs + j0);
    u16x8 sv1 = *reinterpret_cast<const u16x8*>(gs + j0 + 8);
    fx4 av[4], epv[4], env[4];
    #pragma unroll
    for (int q = 0; q < 4; q++) {
      av[q] = *reinterpret_cast<const fx4*>(garow + j0 + q * 4);
      epv[q] = *reinterpret_cast<const fx4*>(gep + j0 + q * 4);
      env[q] = *reinterpret_cast<const fx4*>(gen + j0 + q * 4);
    }
    __syncthreads();  // previous iteration's MFMA reads complete
    *reinterpret_cast<u16x8*>(&Ss[sr][sc]) = sv0;
    *reinterpret_cast<u16x8*>(&Ss[sr][sc + 8]) = sv1;
    bf16x8 pb0, pb1;
    #pragma unroll
    for (int q = 0; q < 4; q++)
      #pragma unroll
      for (int z = 0; z < 4; z++) {
        float pp = Ai * epv[q][z];
        float pn = Bi * env[q][z];
        float p = (pp > Ti ? pp : pn) * av[q][z];
        lsum += p;
        int idx = q * 4 + z;
        if (idx < 8) pb0[idx] = (__bf16)p; else pb1[idx - 8] = (__bf16)p;
      }
    *reinterpret_cast<bf16x8*>(&Ps[pi][pjc]) = pb0;
    *reinterpret_cast<bf16x8*>(&Ps[pi][pjc + 8]) = pb1;
    __syncthreads();  // Ps/Ss visible
    #pragma unroll
    for (int ks = 0; ks < 2; ks++) {
      bf16x8 af = *reinterpret_cast<const bf16x8*>(&Ps[w * 16 + lr][ks * 32 + lk]);
      #pragma unroll
      for (int ni = 0; ni < 4; ni++) {
        bf16x8 bfr = *reinterpret_cast<const bf16x8*>(&Ss[ni * 16 + lr][ks * 32 + lk]);
        acc[ni] = __builtin_amdgcn_mfma_f32_16x16x32_bf16(af, bfr, acc[ni], 0, 0, 0);
      }
    }
  }
  // softmax denominator: 4 threads per row hold disjoint partial sums
  lsum += __shfl_xor(lsum, 1);
  lsum += __shfl_xor(lsum, 2);
  if ((t & 3) == 0) linv[pi] = 1.0f / lsum;
  __syncthreads();
  #pragma unroll
  for (int r = 0; r < 4; r++) {
    int il = w * 16 + (l >> 4) * 4 + r;
    float inv = linv[il];
    #pragma unroll
    for (int ni = 0; ni < 4; ni++)
      hiddenb[(size_t)(i0 + il) * DIN + h * DH + ni * 16 + lr] = f2b(acc[ni][r] * inv);
  }
}

extern "C" void kernel_launch(void* const* d_in, const int* in_sizes, int n_in,
                              void* d_out, int out_size, void* d_ws, size_t ws_size,
                              hipStream_t stream) {
  const float* x = (const float*)d_in[0];
  const float* adj = (const float*)d_in[1];
  const float* W_seq = (const float*)d_in[2];
  const float* a1 = (const float*)d_in[3];
  const float* a2 = (const float*)d_in[4];
  const float* W_out = (const float*)d_in[5];
  const float* b_out = (const float*)d_in[6];

  char* ws = (char*)d_ws;
  u16* xb   = (u16*)(ws);                       // 8 MB
  u16* wsT  = (u16*)(ws + (8u << 20));          // 2 MB
  u16* woT  = (u16*)(ws + (10u << 20));         // 2 MB
  u16* seqb = (u16*)(ws + (12u << 20));         // 8 MB
  u16* seqT = (u16*)(ws + (20u << 20));         // 8 MB
  u16* hid  = (u16*)(ws + (28u << 20));         // 8 MB
  float* s1T  = (float*)(ws + (36u << 20));     // 256 KB
  float* s2H  = s1T + NN * NH;                  // 256 KB
  float* Ep   = s2H + NN * NH;                  // 256 KB
  float* En   = Ep + NN * NH;                   // 256 KB
  float* DmaxB = En + NN * NH;                  // 64 B

  // 1. casts / transposes of weights and x
  cast_kernel<<<4096, 256, 0, stream>>>(x, xb, NN * DIN / 4);
  tcast_kernel<<<dim3(32, 32), 256, 0, stream>>>(W_seq, wsT, DIN, DIN);
  tcast_kernel<<<dim3(32, 32), 256, 0, stream>>>(W_out, woT, DIN, DIN);
  // 2. seq = x @ W_seq  (bf16 out)
  gemm_bt<0><<<dim3(32, 8), 256, 0, stream>>>(xb, wsT, (void*)seqb, nullptr, NN, DIN, DIN);
  // 3. per-head scores
  scores_kernel<<<4096, 256, 0, stream>>>(seqb, a1, a2, s1T, s2H);
  // 4. per-head global max + exp tables
  prep_kernel<<<16, 256, 0, stream>>>(s2H, DmaxB, Ep, En);
  // 5. seq transpose for PV B-operand
  tb16_kernel<<<dim3(32, 128), 256, 0, stream>>>(seqb, seqT, NN, DIN);
  // 6. fused P + PV + denominator
  pv_kernel<<<1024, 256, 0, stream>>>(adj, seqT, s1T, DmaxB, Ep, En, hid);
  // 7. out = elu(hidden @ W_out + b_out)
  gemm_bt<1><<<dim3(32, 8), 256, 0, stream>>>(hid, woT, d_out, b_out, NN, DIN, DIN);
}

// Round 3
// 191.960 us; speedup vs baseline: 1.8149x; 1.5034x over previous
//
#include <hip/hip_runtime.h>
#include <hip/hip_bf16.h>
#include <math.h>

#define NN 4096
#define DIN 1024
#define NH 16
#define DH 64

typedef unsigned short u16;
typedef unsigned long long u64;
typedef u16 u16x4 __attribute__((ext_vector_type(4)));
typedef u16 u16x8 __attribute__((ext_vector_type(8)));
typedef unsigned ux4 __attribute__((ext_vector_type(4)));
typedef float fx4 __attribute__((ext_vector_type(4)));
typedef __bf16 bf16x8 __attribute__((ext_vector_type(8)));

__device__ __forceinline__ u16 f2b(float f) {
  unsigned u = __float_as_uint(f);
  u += 0x7fff + ((u >> 16) & 1);
  return (u16)(u >> 16);
}
__device__ __forceinline__ float b2f(u16 h) {
  return __uint_as_float(((unsigned)h) << 16);
}

// ---------------- cast f32 -> bf16 (flat) ----------------
__global__ __launch_bounds__(256) void cast_kernel(const float* __restrict__ in,
                                                   u16* __restrict__ out, int n4) {
  int i = blockIdx.x * 256 + threadIdx.x;
  if (i < n4) {
    fx4 v = reinterpret_cast<const fx4*>(in)[i];
    u16x4 o;
    o[0] = f2b(v[0]); o[1] = f2b(v[1]); o[2] = f2b(v[2]); o[3] = f2b(v[3]);
    reinterpret_cast<u16x4*>(out)[i] = o;
  }
}

// ---------------- transpose+cast f32[R][C] -> bf16[C][R] ----------------
__global__ __launch_bounds__(256) void tcast_kernel(const float* __restrict__ in,
                                                    u16* __restrict__ out, int R, int C) {
  __shared__ u16 tile[32][33];
  int bc = blockIdx.x * 32, br = blockIdx.y * 32;
  int tx = threadIdx.x & 31, ty = threadIdx.x >> 5;
  #pragma unroll
  for (int r = ty; r < 32; r += 8)
    tile[r][tx] = f2b(in[(size_t)(br + r) * C + bc + tx]);
  __syncthreads();
  #pragma unroll
  for (int r = ty; r < 32; r += 8)
    out[(size_t)(bc + r) * R + br + tx] = tile[tx][r];
}

// ---------------- transpose bf16[R][C] -> bf16[C][R] ----------------
__global__ __launch_bounds__(256) void tb16_kernel(const u16* __restrict__ in,
                                                   u16* __restrict__ out, int R, int C) {
  __shared__ u16 tile[32][33];
  int bc = blockIdx.x * 32, br = blockIdx.y * 32;
  int tx = threadIdx.x & 31, ty = threadIdx.x >> 5;
  #pragma unroll
  for (int r = ty; r < 32; r += 8)
    tile[r][tx] = in[(size_t)(br + r) * C + bc + tx];
  __syncthreads();
  #pragma unroll
  for (int r = ty; r < 32; r += 8)
    out[(size_t)(bc + r) * R + br + tx] = tile[tx][r];
}

// ---------------- bf16 GEMM: C[M][N] = A[M][K] * BT[N][K]^T ----------------
template <int EPI>
__global__ __launch_bounds__(256) void gemm_bt(const u16* __restrict__ A,
                                               const u16* __restrict__ BT,
                                               void* __restrict__ Cv,
                                               const float* __restrict__ bias,
                                               int M, int N, int K) {
  __shared__ __align__(16) u16 As[128][40];
  __shared__ __align__(16) u16 Bs[128][40];
  const int tid = threadIdx.x;
  const int i0 = blockIdx.x * 128, n0 = blockIdx.y * 128;
  const int w = tid >> 6, l = tid & 63;
  const int wr = w >> 1, wc = w & 1;
  const int lr = l & 15, lk = (l >> 4) * 8;
  const int srow = tid >> 1, sk = (tid & 1) * 16;
  fx4 acc[4][4] = {};
  const u16* ga = A + (size_t)(i0 + srow) * K + sk;
  const u16* gb = BT + (size_t)(n0 + srow) * K + sk;
  for (int k0 = 0; k0 < K; k0 += 32) {
    u16x8 a0 = *reinterpret_cast<const u16x8*>(ga + k0);
    u16x8 a1 = *reinterpret_cast<const u16x8*>(ga + k0 + 8);
    u16x8 b0 = *reinterpret_cast<const u16x8*>(gb + k0);
    u16x8 b1 = *reinterpret_cast<const u16x8*>(gb + k0 + 8);
    __syncthreads();
    *reinterpret_cast<u16x8*>(&As[srow][sk]) = a0;
    *reinterpret_cast<u16x8*>(&As[srow][sk + 8]) = a1;
    *reinterpret_cast<u16x8*>(&Bs[srow][sk]) = b0;
    *reinterpret_cast<u16x8*>(&Bs[srow][sk + 8]) = b1;
    __syncthreads();
    bf16x8 af[4], bfr[4];
    #pragma unroll
    for (int mi = 0; mi < 4; mi++)
      af[mi] = *reinterpret_cast<const bf16x8*>(&As[wr * 64 + mi * 16 + lr][lk]);
    #pragma unroll
    for (int ni = 0; ni < 4; ni++)
      bfr[ni] = *reinterpret_cast<const bf16x8*>(&Bs[wc * 64 + ni * 16 + lr][lk]);
    #pragma unroll
    for (int mi = 0; mi < 4; mi++)
      #pragma unroll
      for (int ni = 0; ni < 4; ni++)
        acc[mi][ni] = __builtin_amdgcn_mfma_f32_16x16x32_bf16(af[mi], bfr[ni], acc[mi][ni], 0, 0, 0);
  }
  const int orow = wr * 64 + (l >> 4) * 4;
  const int ocol = wc * 64 + lr;
  if (EPI == 0) {
    u16* Cb = (u16*)Cv;
    #pragma unroll
    for (int mi = 0; mi < 4; mi++)
      #pragma unroll
      for (int r = 0; r < 4; r++)
        #pragma unroll
        for (int ni = 0; ni < 4; ni++)
          Cb[(size_t)(i0 + orow + mi * 16 + r) * N + n0 + ocol + ni * 16] = f2b(acc[mi][ni][r]);
  } else {
    float* Cf = (float*)Cv;
    #pragma unroll
    for (int mi = 0; mi < 4; mi++)
      #pragma unroll
      for (int r = 0; r < 4; r++)
        #pragma unroll
        for (int ni = 0; ni < 4; ni++) {
          int col = n0 + ocol + ni * 16;
          float v = acc[mi][ni][r] + bias[col];
          Cf[(size_t)(i0 + orow + mi * 16 + r) * N + col] = v > 0.f ? v : expm1f(v);
        }
  }
}

// ---------------- per-head scalar scores ----------------
__global__ __launch_bounds__(256) void scores_kernel(const u16* __restrict__ seqb,
                                                     const float* __restrict__ a1,
                                                     const float* __restrict__ a2,
                                                     float* __restrict__ s1T,
                                                     float* __restrict__ s2H) {
  int n = blockIdx.x, t = threadIdx.x;
  u16x4 v = reinterpret_cast<const u16x4*>(seqb)[n * 256 + t];
  fx4 w1 = reinterpret_cast<const fx4*>(a1)[t & 15];
  fx4 w2 = reinterpret_cast<const fx4*>(a2)[t & 15];
  float s1 = 0.f, s2 = 0.f;
  #pragma unroll
  for (int e = 0; e < 4; e++) {
    float f = b2f(v[e]);
    s1 += f * w1[e];
    s2 += f * w2[e];
  }
  #pragma unroll
  for (int off = 1; off < 16; off <<= 1) {
    s1 += __shfl_xor(s1, off);
    s2 += __shfl_xor(s2, off);
  }
  if ((t & 15) == 0) {
    int h = t >> 4;
    s1T[n * NH + h] = s1;
    s2H[h * NN + n] = s2;
  }
}

// ---------------- per-head global max + packed bf16 exp tables ----------------
__global__ __launch_bounds__(256) void prep_kernel(const float* __restrict__ s2H,
                                                   float* __restrict__ Dmax,
                                                   unsigned* __restrict__ tab) {
  __shared__ float red[4];
  const int h = blockIdx.x, t = threadIdx.x;
  const fx4* d = reinterpret_cast<const fx4*>(s2H + (size_t)h * NN);
  fx4 v[4];
  float mx = -3e38f;
  #pragma unroll
  for (int q = 0; q < 4; q++) {
    v[q] = d[t + 256 * q];
    #pragma unroll
    for (int z = 0; z < 4; z++) mx = fmaxf(mx, v[q][z]);
  }
  #pragma unroll
  for (int off = 1; off < 64; off <<= 1) mx = fmaxf(mx, __shfl_xor(mx, off));
  if ((t & 63) == 0) red[t >> 6] = mx;
  __syncthreads();
  mx = fmaxf(fmaxf(red[0], red[1]), fmaxf(red[2], red[3]));
  if (t == 0) Dmax[h] = mx;
  #pragma unroll
  for (int q = 0; q < 4; q++) {
    ux4 wd;
    #pragma unroll
    for (int z = 0; z < 4; z++) {
      float ep = __expf(v[q][z]);
      float en = __expf(0.2f * v[q][z]);
      wd[z] = (unsigned)f2b(ep) | ((unsigned)f2b(en) << 16);  // ep low, en high
    }
    reinterpret_cast<ux4*>(tab + (size_t)h * NN)[t + 256 * q] = wd;
  }
}

// ---------------- adjacency -> bitmask (u64 per 64 cols) ----------------
__global__ __launch_bounds__(256) void mask_kernel(const float* __restrict__ adj,
                                                   u64* __restrict__ maskQ) {
  const int row = blockIdx.x, w = threadIdx.x >> 6, l = threadIdx.x & 63;
  const float* ar = adj + (size_t)row * NN;
  #pragma unroll
  for (int i = 0; i < 16; i++) {
    int word = w * 16 + i;
    float v = ar[word * 64 + l];
    u64 m = __ballot(v > 0.5f);
    if (l == 0) maskQ[(size_t)row * 64 + word] = m;
  }
}

// ---------------- fused P-in-register + PV + MFMA row-sums ----------------
__global__ __launch_bounds__(256) void pv_kernel(const u64* __restrict__ maskQ,
                                                 const u16* __restrict__ seqT,
                                                 const float* __restrict__ s1T,
                                                 const float* __restrict__ Dmax,
                                                 const unsigned* __restrict__ tab,
                                                 u16* __restrict__ hiddenb) {
  __shared__ __align__(16) u16 Ss[2][64][72];
  const int h = blockIdx.x & 15, it = blockIdx.x >> 4, i0 = it * 64;
  const int t = threadIdx.x, w = t >> 6, l = t & 63;
  const int lr = l & 15, hi = l >> 4, lk = hi * 8;
  const int myrow = w * 16 + lr;
  const float ci = s1T[(i0 + myrow) * NH + h];
  const float Dm = Dmax[h];
  float mi = ci + Dm;
  mi = mi > 0.f ? mi : 0.2f * mi;
  const float Ai = __expf(ci - mi), Bi = __expf(0.2f * ci - mi);
  const int sr = t >> 2, sc = (t & 3) * 16;
  const u16* gs = seqT + (size_t)(h * DH + sr) * NN + sc;
  const u64* gm = maskQ + (size_t)(i0 + myrow) * 64;
  const unsigned* gtab = tab + (size_t)h * NN + lk;
  fx4 acc[4] = {};
  fx4 acc1 = {};
  bf16x8 ones;
  #pragma unroll
  for (int e = 0; e < 8; e++) ones[e] = (__bf16)1.0f;

  // prologue: stage j0=0 tile, prefetch mask/tab for j0=0
  u16x8 sv0 = *reinterpret_cast<const u16x8*>(gs);
  u16x8 sv1 = *reinterpret_cast<const u16x8*>(gs + 8);
  u64 mc = gm[0];
  ux4 tc0 = *reinterpret_cast<const ux4*>(gtab);
  ux4 tc1 = *reinterpret_cast<const ux4*>(gtab + 4);
  ux4 tc2 = *reinterpret_cast<const ux4*>(gtab + 32);
  ux4 tc3 = *reinterpret_cast<const ux4*>(gtab + 36);
  *reinterpret_cast<u16x8*>(&Ss[0][sr][sc]) = sv0;
  *reinterpret_cast<u16x8*>(&Ss[0][sr][sc + 8]) = sv1;
  __syncthreads();

  #pragma unroll 2
  for (int jt = 0; jt < 64; jt++) {
    const int cur = jt & 1;
    const int jn = ((jt + 1) & 63) * 64;
    // depth-1 prefetch: seqT tile, mask word, tab words for next iter
    u16x8 nv0 = *reinterpret_cast<const u16x8*>(gs + jn);
    u16x8 nv1 = *reinterpret_cast<const u16x8*>(gs + jn + 8);
    u64 mn = gm[jn >> 6];
    ux4 nt0 = *reinterpret_cast<const ux4*>(gtab + jn);
    ux4 nt1 = *reinterpret_cast<const ux4*>(gtab + jn + 4);
    ux4 nt2 = *reinterpret_cast<const ux4*>(gtab + jn + 32);
    ux4 nt3 = *reinterpret_cast<const ux4*>(gtab + jn + 36);
    // ---- ks = 0 ----
    {
      unsigned mb = (unsigned)(mc >> lk) & 0xffu;
      bf16x8 af;
      #pragma unroll
      for (int e = 0; e < 4; e++) {
        unsigned wd = tc0[e];
        float p = fmaxf(Ai * __uint_as_float(wd << 16),
                        Bi * __uint_as_float(wd & 0xffff0000u));
        p = ((mb >> e) & 1) ? p : 0.f;
        af[e] = (__bf16)p;
      }
      #pragma unroll
      for (int e = 0; e < 4; e++) {
        unsigned wd = tc1[e];
        float p = fmaxf(Ai * __uint_as_float(wd << 16),
                        Bi * __uint_as_float(wd & 0xffff0000u));
        p = ((mb >> (4 + e)) & 1) ? p : 0.f;
        af[4 + e] = (__bf16)p;
      }
      #pragma unroll
      for (int ni = 0; ni < 4; ni++) {
        bf16x8 bfr = *reinterpret_cast<const bf16x8*>(&Ss[cur][ni * 16 + lr][lk]);
        acc[ni] = __builtin_amdgcn_mfma_f32_16x16x32_bf16(af, bfr, acc[ni], 0, 0, 0);
      }
      acc1 = __builtin_amdgcn_mfma_f32_16x16x32_bf16(af, ones, acc1, 0, 0, 0);
    }
    // ---- ks = 1 ----
    {
      unsigned mb = (unsigned)(mc >> (lk + 32)) & 0xffu;
      bf16x8 af;
      #pragma unroll
      for (int e = 0; e < 4; e++) {
        unsigned wd = tc2[e];
        float p = fmaxf(Ai * __uint_as_float(wd << 16),
                        Bi * __uint_as_float(wd & 0xffff0000u));
        p = ((mb >> e) & 1) ? p : 0.f;
        af[e] = (__bf16)p;
      }
      #pragma unroll
      for (int e = 0; e < 4; e++) {
        unsigned wd = tc3[e];
        float p = fmaxf(Ai * __uint_as_float(wd << 16),
                        Bi * __uint_as_float(wd & 0xffff0000u));
        p = ((mb >> (4 + e)) & 1) ? p : 0.f;
        af[4 + e] = (__bf16)p;
      }
      #pragma unroll
      for (int ni = 0; ni < 4; ni++) {
        bf16x8 bfr = *reinterpret_cast<const bf16x8*>(&Ss[cur][ni * 16 + lr][32 + lk]);
        acc[ni] = __builtin_amdgcn_mfma_f32_16x16x32_bf16(af, bfr, acc[ni], 0, 0, 0);
      }
      acc1 = __builtin_amdgcn_mfma_f32_16x16x32_bf16(af, ones, acc1, 0, 0, 0);
    }
    // stage next tile into the other buffer; one barrier per iter
    *reinterpret_cast<u16x8*>(&Ss[cur ^ 1][sr][sc]) = nv0;
    *reinterpret_cast<u16x8*>(&Ss[cur ^ 1][sr][sc + 8]) = nv1;
    __syncthreads();
    mc = mn; tc0 = nt0; tc1 = nt1; tc2 = nt2; tc3 = nt3;
  }

  #pragma unroll
  for (int r = 0; r < 4; r++) {
    const int il = w * 16 + hi * 4 + r;
    float inv = 1.0f / acc1[r];
    #pragma unroll
    for (int ni = 0; ni < 4; ni++)
      hiddenb[(size_t)(i0 + il) * DIN + h * DH + ni * 16 + lr] = f2b(acc[ni][r] * inv);
  }
}

extern "C" void kernel_launch(void* const* d_in, const int* in_sizes, int n_in,
                              void* d_out, int out_size, void* d_ws, size_t ws_size,
                              hipStream_t stream) {
  const float* x = (const float*)d_in[0];
  const float* adj = (const float*)d_in[1];
  const float* W_seq = (const float*)d_in[2];
  const float* a1 = (const float*)d_in[3];
  const float* a2 = (const float*)d_in[4];
  const float* W_out = (const float*)d_in[5];
  const float* b_out = (const float*)d_in[6];

  char* ws = (char*)d_ws;
  u16* xb   = (u16*)(ws);                       // 8 MB
  u16* wsT  = (u16*)(ws + (8u << 20));          // 2 MB
  u16* woT  = (u16*)(ws + (10u << 20));         // 2 MB
  u16* seqb = (u16*)(ws + (12u << 20));         // 8 MB
  u16* seqT = (u16*)(ws + (20u << 20));         // 8 MB
  u16* hid  = (u16*)(ws + (28u << 20));         // 8 MB
  float* s1T  = (float*)(ws + (36u << 20));     // 256 KB
  float* s2H  = s1T + NN * NH;                  // 256 KB
  unsigned* tab = (unsigned*)(s2H + NN * NH);   // 256 KB
  float* DmaxB = (float*)(tab + NN * NH);       // 64 B
  u64* maskQ = (u64*)(ws + (37u << 20));        // 2 MB

  cast_kernel<<<4096, 256, 0, stream>>>(x, xb, NN * DIN / 4);
  tcast_kernel<<<dim3(32, 32), 256, 0, stream>>>(W_seq, wsT, DIN, DIN);
  tcast_kernel<<<dim3(32, 32), 256, 0, stream>>>(W_out, woT, DIN, DIN);
  mask_kernel<<<4096, 256, 0, stream>>>(adj, maskQ);
  gemm_bt<0><<<dim3(32, 8), 256, 0, stream>>>(xb, wsT, (void*)seqb, nullptr, NN, DIN, DIN);
  scores_kernel<<<4096, 256, 0, stream>>>(seqb, a1, a2, s1T, s2H);
  prep_kernel<<<16, 256, 0, stream>>>(s2H, DmaxB, tab);
  tb16_kernel<<<dim3(32, 128), 256, 0, stream>>>(seqb, seqT, NN, DIN);
  pv_kernel<<<1024, 256, 0, stream>>>(maskQ, seqT, s1T, DmaxB, tab, hid);
  gemm_bt<1><<<dim3(32, 8), 256, 0, stream>>>(hid, woT, d_out, b_out, NN, DIN, DIN);
}

// Round 4
// 187.904 us; speedup vs baseline: 1.8541x; 1.0216x over previous
//
#include <hip/hip_runtime.h>
#include <hip/hip_bf16.h>
#include <math.h>

#define NN 4096
#define DIN 1024
#define NH 16
#define DH 64

typedef unsigned short u16;
typedef unsigned long long u64;
typedef u16 u16x4 __attribute__((ext_vector_type(4)));
typedef u16 u16x8 __attribute__((ext_vector_type(8)));
typedef unsigned ux2 __attribute__((ext_vector_type(2)));
typedef unsigned ux4 __attribute__((ext_vector_type(4)));
typedef float fx4 __attribute__((ext_vector_type(4)));
typedef __bf16 bf16x8 __attribute__((ext_vector_type(8)));
typedef _Float16 h16x8 __attribute__((ext_vector_type(8)));

__device__ __forceinline__ u16 f2b(float f) {
  unsigned u = __float_as_uint(f);
  u += 0x7fff + ((u >> 16) & 1);
  return (u16)(u >> 16);
}
__device__ __forceinline__ float b2f(u16 h) {
  return __uint_as_float(((unsigned)h) << 16);
}
__device__ __forceinline__ u16 f2h_bits(float f) {
  _Float16 h = (_Float16)f;
  return __builtin_bit_cast(unsigned short, h);
}
__device__ __forceinline__ unsigned pack2h(float f) {
  unsigned hb = (unsigned)f2h_bits(f);
  return hb | (hb << 16);
}
__device__ __forceinline__ unsigned pk_mul(unsigned a, unsigned b) {
  unsigned d;
  asm("v_pk_mul_f16 %0, %1, %2" : "=v"(d) : "v"(a), "v"(b));
  return d;
}
__device__ __forceinline__ unsigned pk_max(unsigned a, unsigned b) {
  unsigned d;
  asm("v_pk_max_f16 %0, %1, %2" : "=v"(d) : "v"(a), "v"(b));
  return d;
}

// ---------------- cast f32 -> bf16 (flat) ----------------
__global__ __launch_bounds__(256) void cast_kernel(const float* __restrict__ in,
                                                   u16* __restrict__ out, int n4) {
  int i = blockIdx.x * 256 + threadIdx.x;
  if (i < n4) {
    fx4 v = reinterpret_cast<const fx4*>(in)[i];
    u16x4 o;
    o[0] = f2b(v[0]); o[1] = f2b(v[1]); o[2] = f2b(v[2]); o[3] = f2b(v[3]);
    reinterpret_cast<u16x4*>(out)[i] = o;
  }
}

// ---------------- transpose+cast f32[R][C] -> bf16[C][R] ----------------
__global__ __launch_bounds__(256) void tcast_kernel(const float* __restrict__ in,
                                                    u16* __restrict__ out, int R, int C) {
  __shared__ u16 tile[32][33];
  int bc = blockIdx.x * 32, br = blockIdx.y * 32;
  int tx = threadIdx.x & 31, ty = threadIdx.x >> 5;
  #pragma unroll
  for (int r = ty; r < 32; r += 8)
    tile[r][tx] = f2b(in[(size_t)(br + r) * C + bc + tx]);
  __syncthreads();
  #pragma unroll
  for (int r = ty; r < 32; r += 8)
    out[(size_t)(bc + r) * R + br + tx] = tile[tx][r];
}

// ---------------- transpose bf16[R][C] -> f16-bits[C][R] ----------------
__global__ __launch_bounds__(256) void tb16h_kernel(const u16* __restrict__ in,
                                                    u16* __restrict__ out, int R, int C) {
  __shared__ u16 tile[32][33];
  int bc = blockIdx.x * 32, br = blockIdx.y * 32;
  int tx = threadIdx.x & 31, ty = threadIdx.x >> 5;
  #pragma unroll
  for (int r = ty; r < 32; r += 8)
    tile[r][tx] = f2h_bits(b2f(in[(size_t)(br + r) * C + bc + tx]));
  __syncthreads();
  #pragma unroll
  for (int r = ty; r < 32; r += 8)
    out[(size_t)(bc + r) * R + br + tx] = tile[tx][r];
}

// ---------------- bf16 GEMM: C[M][N] = A[M][K] * BT[N][K]^T ----------------
template <int EPI>
__global__ __launch_bounds__(256) void gemm_bt(const u16* __restrict__ A,
                                               const u16* __restrict__ BT,
                                               void* __restrict__ Cv,
                                               const float* __restrict__ bias,
                                               int M, int N, int K) {
  __shared__ __align__(16) u16 As[128][40];
  __shared__ __align__(16) u16 Bs[128][40];
  const int tid = threadIdx.x;
  const int i0 = blockIdx.x * 128, n0 = blockIdx.y * 128;
  const int w = tid >> 6, l = tid & 63;
  const int wr = w >> 1, wc = w & 1;
  const int lr = l & 15, lk = (l >> 4) * 8;
  const int srow = tid >> 1, sk = (tid & 1) * 16;
  fx4 acc[4][4] = {};
  const u16* ga = A + (size_t)(i0 + srow) * K + sk;
  const u16* gb = BT + (size_t)(n0 + srow) * K + sk;
  for (int k0 = 0; k0 < K; k0 += 32) {
    u16x8 a0 = *reinterpret_cast<const u16x8*>(ga + k0);
    u16x8 a1 = *reinterpret_cast<const u16x8*>(ga + k0 + 8);
    u16x8 b0 = *reinterpret_cast<const u16x8*>(gb + k0);
    u16x8 b1 = *reinterpret_cast<const u16x8*>(gb + k0 + 8);
    __syncthreads();
    *reinterpret_cast<u16x8*>(&As[srow][sk]) = a0;
    *reinterpret_cast<u16x8*>(&As[srow][sk + 8]) = a1;
    *reinterpret_cast<u16x8*>(&Bs[srow][sk]) = b0;
    *reinterpret_cast<u16x8*>(&Bs[srow][sk + 8]) = b1;
    __syncthreads();
    bf16x8 af[4], bfr[4];
    #pragma unroll
    for (int mi = 0; mi < 4; mi++)
      af[mi] = *reinterpret_cast<const bf16x8*>(&As[wr * 64 + mi * 16 + lr][lk]);
    #pragma unroll
    for (int ni = 0; ni < 4; ni++)
      bfr[ni] = *reinterpret_cast<const bf16x8*>(&Bs[wc * 64 + ni * 16 + lr][lk]);
    #pragma unroll
    for (int mi = 0; mi < 4; mi++)
      #pragma unroll
      for (int ni = 0; ni < 4; ni++)
        acc[mi][ni] = __builtin_amdgcn_mfma_f32_16x16x32_bf16(af[mi], bfr[ni], acc[mi][ni], 0, 0, 0);
  }
  const int orow = wr * 64 + (l >> 4) * 4;
  const int ocol = wc * 64 + lr;
  if (EPI == 0) {
    u16* Cb = (u16*)Cv;
    #pragma unroll
    for (int mi = 0; mi < 4; mi++)
      #pragma unroll
      for (int r = 0; r < 4; r++)
        #pragma unroll
        for (int ni = 0; ni < 4; ni++)
          Cb[(size_t)(i0 + orow + mi * 16 + r) * N + n0 + ocol + ni * 16] = f2b(acc[mi][ni][r]);
  } else {
    float* Cf = (float*)Cv;
    #pragma unroll
    for (int mi = 0; mi < 4; mi++)
      #pragma unroll
      for (int r = 0; r < 4; r++)
        #pragma unroll
        for (int ni = 0; ni < 4; ni++) {
          int col = n0 + ocol + ni * 16;
          float v = acc[mi][ni][r] + bias[col];
          Cf[(size_t)(i0 + orow + mi * 16 + r) * N + col] = v > 0.f ? v : expm1f(v);
        }
  }
}

// ---------------- per-head scalar scores ----------------
__global__ __launch_bounds__(256) void scores_kernel(const u16* __restrict__ seqb,
                                                     const float* __restrict__ a1,
                                                     const float* __restrict__ a2,
                                                     float* __restrict__ s1T,
                                                     float* __restrict__ s2H) {
  int n = blockIdx.x, t = threadIdx.x;
  u16x4 v = reinterpret_cast<const u16x4*>(seqb)[n * 256 + t];
  fx4 w1 = reinterpret_cast<const fx4*>(a1)[t & 15];
  fx4 w2 = reinterpret_cast<const fx4*>(a2)[t & 15];
  float s1 = 0.f, s2 = 0.f;
  #pragma unroll
  for (int e = 0; e < 4; e++) {
    float f = b2f(v[e]);
    s1 += f * w1[e];
    s2 += f * w2[e];
  }
  #pragma unroll
  for (int off = 1; off < 16; off <<= 1) {
    s1 += __shfl_xor(s1, off);
    s2 += __shfl_xor(s2, off);
  }
  if ((t & 15) == 0) {
    int h = t >> 4;
    s1T[n * NH + h] = s1;
    s2H[h * NN + n] = s2;
  }
}

// ---------------- per-head global max + packed f16 exp tables ----------------
__global__ __launch_bounds__(256) void prep_kernel(const float* __restrict__ s2H,
                                                   float* __restrict__ Dmax,
                                                   unsigned* __restrict__ epH2,
                                                   unsigned* __restrict__ enH2) {
  __shared__ float red[4];
  __shared__ float sDm;
  const int h = blockIdx.x, t = threadIdx.x;
  const fx4* d = reinterpret_cast<const fx4*>(s2H + (size_t)h * NN);
  fx4 v[4];
  float mx = -3e38f;
  #pragma unroll
  for (int q = 0; q < 4; q++) {
    v[q] = d[t * 4 + q];
    #pragma unroll
    for (int z = 0; z < 4; z++) mx = fmaxf(mx, v[q][z]);
  }
  #pragma unroll
  for (int off = 1; off < 64; off <<= 1) mx = fmaxf(mx, __shfl_xor(mx, off));
  if ((t & 63) == 0) red[t >> 6] = mx;
  __syncthreads();
  if (t == 0) {
    float m = fmaxf(fmaxf(red[0], red[1]), fmaxf(red[2], red[3]));
    sDm = m;
    Dmax[h] = m;
  }
  __syncthreads();
  const float Dm = sDm;
  #pragma unroll
  for (int q = 0; q < 8; q++) {
    float d0 = v[q >> 1][(q & 1) * 2];
    float d1 = v[q >> 1][(q & 1) * 2 + 1];
    unsigned ep = (unsigned)f2h_bits(__expf(d0 - Dm)) |
                  ((unsigned)f2h_bits(__expf(d1 - Dm)) << 16);
    unsigned en = (unsigned)f2h_bits(__expf(0.2f * (d0 - Dm))) |
                  ((unsigned)f2h_bits(__expf(0.2f * (d1 - Dm))) << 16);
    epH2[h * 2048 + t * 8 + q] = ep;
    enH2[h * 2048 + t * 8 + q] = en;
  }
}

// ---------------- adjacency -> byte mask (0xFF / 0x00 per col) ----------------
__global__ __launch_bounds__(256) void maskb_kernel(const float* __restrict__ adj,
                                                    unsigned char* __restrict__ mb) {
  size_t g = (size_t)blockIdx.x * 256 + threadIdx.x;   // 16 floats per thread
  const fx4* ap = reinterpret_cast<const fx4*>(adj) + g * 4;
  ux4 o;
  #pragma unroll
  for (int q = 0; q < 4; q++) {
    fx4 a = ap[q];
    unsigned b0 = a[0] > 0.5f ? 0xFFu : 0u;
    unsigned b1 = a[1] > 0.5f ? 0xFFu : 0u;
    unsigned b2 = a[2] > 0.5f ? 0xFFu : 0u;
    unsigned b3 = a[3] > 0.5f ? 0xFFu : 0u;
    o[q] = b0 | (b1 << 8) | (b2 << 16) | (b3 << 24);
  }
  reinterpret_cast<ux4*>(mb)[g] = o;
}

// ---------------- fused packed-f16 P-build + PV + MFMA row-sums ----------------
// block = 128 rows x 1 head; 4 waves x 32 rows (2 fragments each)
__global__ __launch_bounds__(256, 2) void pv_kernel(const unsigned char* __restrict__ maskB,
                                                    const u16* __restrict__ seqTh,
                                                    const float* __restrict__ s1T,
                                                    const float* __restrict__ Dmax,
                                                    const unsigned* __restrict__ epH2,
                                                    const unsigned* __restrict__ enH2,
                                                    u16* __restrict__ hiddenb) {
  __shared__ __align__(16) u16 Ss[2][64][72];
  const int h = blockIdx.x & 15, it = blockIdx.x >> 4, i0 = it * 128;
  const int t = threadIdx.x, w = t >> 6, l = t & 63;
  const int lr = l & 15, hi = l >> 4, lk = hi * 8;
  const float Dm = Dmax[h];
  unsigned Ai2[2], Bi2[2];
  int arow[2];
  #pragma unroll
  for (int m = 0; m < 2; m++) {
    int row = i0 + w * 32 + m * 16 + lr;
    arow[m] = row;
    float c = s1T[row * NH + h];
    float mi = c + Dm;
    mi = mi > 0.f ? mi : 0.2f * mi;
    Ai2[m] = pack2h(__expf(c + Dm - mi));
    Bi2[m] = pack2h(__expf(0.2f * (c + Dm) - mi));
  }
  const int sr = t >> 2, sc = (t & 3) * 16;
  const u16* gs = seqTh + (size_t)(h * DH + sr) * NN + sc;
  const unsigned* gep = epH2 + h * 2048 + hi * 4;
  const unsigned* gen = enH2 + h * 2048 + hi * 4;
  const unsigned char* gm[2];
  gm[0] = maskB + (size_t)arow[0] * NN + lk;
  gm[1] = maskB + (size_t)arow[1] * NN + lk;
  fx4 acc[2][4] = {};
  fx4 acc1[2] = {};
  h16x8 ones;
  #pragma unroll
  for (int e = 0; e < 8; e++) ones[e] = (_Float16)1.0f;

  // prologue: tile 0
  u16x8 sv0 = *reinterpret_cast<const u16x8*>(gs);
  u16x8 sv1 = *reinterpret_cast<const u16x8*>(gs + 8);
  ux4 epc[2], enc[2];
  ux2 mkc[2][2];
  #pragma unroll
  for (int ks = 0; ks < 2; ks++) {
    epc[ks] = *reinterpret_cast<const ux4*>(gep + ks * 16);
    enc[ks] = *reinterpret_cast<const ux4*>(gen + ks * 16);
    #pragma unroll
    for (int m = 0; m < 2; m++)
      mkc[m][ks] = *reinterpret_cast<const ux2*>(gm[m] + ks * 32);
  }
  *reinterpret_cast<u16x8*>(&Ss[0][sr][sc]) = sv0;
  *reinterpret_cast<u16x8*>(&Ss[0][sr][sc + 8]) = sv1;
  __syncthreads();

  #pragma unroll 2
  for (int jt = 0; jt < 64; jt++) {
    const int cur = jt & 1;
    const int jb = (jt + 1) & 63;
    // depth-1 prefetch of everything for jt+1
    u16x8 nsv0 = *reinterpret_cast<const u16x8*>(gs + jb * 64);
    u16x8 nsv1 = *reinterpret_cast<const u16x8*>(gs + jb * 64 + 8);
    ux4 nep[2], nen[2];
    ux2 nmk[2][2];
    #pragma unroll
    for (int ks = 0; ks < 2; ks++) {
      nep[ks] = *reinterpret_cast<const ux4*>(gep + jb * 32 + ks * 16);
      nen[ks] = *reinterpret_cast<const ux4*>(gen + jb * 32 + ks * 16);
      #pragma unroll
      for (int m = 0; m < 2; m++)
        nmk[m][ks] = *reinterpret_cast<const ux2*>(gm[m] + jb * 64 + ks * 32);
    }
    // compute current tile
    #pragma unroll
    for (int ks = 0; ks < 2; ks++) {
      h16x8 bfr[4];
      #pragma unroll
      for (int ni = 0; ni < 4; ni++)
        bfr[ni] = *reinterpret_cast<const h16x8*>(&Ss[cur][ni * 16 + lr][ks * 32 + lk]);
      #pragma unroll
      for (int m = 0; m < 2; m++) {
        unsigned w0 = __builtin_amdgcn_perm(0u, mkc[m][ks][0], 0x01010000u);
        unsigned w1 = __builtin_amdgcn_perm(0u, mkc[m][ks][0], 0x03030202u);
        unsigned w2 = __builtin_amdgcn_perm(0u, mkc[m][ks][1], 0x01010000u);
        unsigned w3 = __builtin_amdgcn_perm(0u, mkc[m][ks][1], 0x03030202u);
        ux4 afw;
        afw[0] = pk_max(pk_mul(Ai2[m], epc[ks][0]), pk_mul(Bi2[m], enc[ks][0])) & w0;
        afw[1] = pk_max(pk_mul(Ai2[m], epc[ks][1]), pk_mul(Bi2[m], enc[ks][1])) & w1;
        afw[2] = pk_max(pk_mul(Ai2[m], epc[ks][2]), pk_mul(Bi2[m], enc[ks][2])) & w2;
        afw[3] = pk_max(pk_mul(Ai2[m], epc[ks][3]), pk_mul(Bi2[m], enc[ks][3])) & w3;
        h16x8 A = __builtin_bit_cast(h16x8, afw);
        #pragma unroll
        for (int ni = 0; ni < 4; ni++)
          acc[m][ni] = __builtin_amdgcn_mfma_f32_16x16x32_f16(A, bfr[ni], acc[m][ni], 0, 0, 0);
        acc1[m] = __builtin_amdgcn_mfma_f32_16x16x32_f16(A, ones, acc1[m], 0, 0, 0);
      }
    }
    // stage next tile into other buffer
    *reinterpret_cast<u16x8*>(&Ss[cur ^ 1][sr][sc]) = nsv0;
    *reinterpret_cast<u16x8*>(&Ss[cur ^ 1][sr][sc + 8]) = nsv1;
    __syncthreads();
    sv0 = nsv0; sv1 = nsv1;
    #pragma unroll
    for (int ks = 0; ks < 2; ks++) {
      epc[ks] = nep[ks];
      enc[ks] = nen[ks];
      #pragma unroll
      for (int m = 0; m < 2; m++) mkc[m][ks] = nmk[m][ks];
    }
  }

  #pragma unroll
  for (int m = 0; m < 2; m++)
    #pragma unroll
    for (int r = 0; r < 4; r++) {
      int row = i0 + w * 32 + m * 16 + hi * 4 + r;
      float inv = 1.0f / acc1[m][r];
      #pragma unroll
      for (int ni = 0; ni < 4; ni++)
        hiddenb[(size_t)row * DIN + h * DH + ni * 16 + lr] = f2b(acc[m][ni][r] * inv);
    }
}

extern "C" void kernel_launch(void* const* d_in, const int* in_sizes, int n_in,
                              void* d_out, int out_size, void* d_ws, size_t ws_size,
                              hipStream_t stream) {
  const float* x = (const float*)d_in[0];
  const float* adj = (const float*)d_in[1];
  const float* W_seq = (const float*)d_in[2];
  const float* a1 = (const float*)d_in[3];
  const float* a2 = (const float*)d_in[4];
  const float* W_out = (const float*)d_in[5];
  const float* b_out = (const float*)d_in[6];

  char* ws = (char*)d_ws;
  u16* wsT   = (u16*)(ws);                         // 2 MB
  u16* woT   = (u16*)(ws + (2u << 20));            // 2 MB
  u16* seqb  = (u16*)(ws + (4u << 20));            // 8 MB (bf16)
  u16* seqTh = (u16*)(ws + (12u << 20));           // 8 MB (f16 bits)
  u16* hid   = (u16*)(ws + (20u << 20));           // 8 MB (bf16)
  float* s1T = (float*)(ws + (28u << 20));         // 256 KB
  float* s2H = s1T + NN * NH;                      // 256 KB
  unsigned* epH2 = (unsigned*)(s2H + NN * NH);     // 128 KB
  unsigned* enH2 = epH2 + NH * 2048;               // 128 KB
  float* DmaxB = (float*)(enH2 + NH * 2048);       // 64 B
  // xb aliases the mask region: xb dead after gemm1; maskb_kernel runs after gemm1.
  u16* xb = (u16*)(ws + (29u << 20));              // 8 MB
  unsigned char* maskB = (unsigned char*)(ws + (29u << 20));  // 16 MB -> total 45 MB

  cast_kernel<<<4096, 256, 0, stream>>>(x, xb, NN * DIN / 4);
  tcast_kernel<<<dim3(32, 32), 256, 0, stream>>>(W_seq, wsT, DIN, DIN);
  tcast_kernel<<<dim3(32, 32), 256, 0, stream>>>(W_out, woT, DIN, DIN);
  gemm_bt<0><<<dim3(32, 8), 256, 0, stream>>>(xb, wsT, (void*)seqb, nullptr, NN, DIN, DIN);
  scores_kernel<<<4096, 256, 0, stream>>>(seqb, a1, a2, s1T, s2H);
  prep_kernel<<<16, 256, 0, stream>>>(s2H, DmaxB, epH2, enH2);
  tb16h_kernel<<<dim3(32, 128), 256, 0, stream>>>(seqb, seqTh, NN, DIN);
  maskb_kernel<<<4096, 256, 0, stream>>>(adj, maskB);   // after gemm1: xb region reused
  pv_kernel<<<512, 256, 0, stream>>>(maskB, seqTh, s1T, DmaxB, epH2, enH2, hid);
  gemm_bt<1><<<dim3(32, 8), 256, 0, stream>>>(hid, woT, d_out, b_out, NN, DIN, DIN);
}